// Round 5
// baseline (210.818 us; speedup 1.0000x reference)
//
#include <hip/hip_runtime.h>
#include <hip/hip_bf16.h>

#define EMBED 128   // node embedding dim
#define HID   64    // hidden dim

typedef unsigned short ushort;
typedef ushort ushort8 __attribute__((ext_vector_type(8)));

__device__ __forceinline__ float bf2f(ushort u) {
    union { unsigned int i; float f; } c;
    c.i = ((unsigned int)u) << 16;
    return c.f;
}
__device__ __forceinline__ ushort f2bf(float f) {
    union { float f; unsigned int i; } c;
    c.f = f;
    // RTNE
    unsigned int r = c.i + 0x7FFFu + ((c.i >> 16) & 1u);
    return (ushort)(r >> 16);
}

// ---------------------------------------------------------------------------
// Kernel 1: node projection, one j-half per block.
//   half=0: P[n][j]    = (Z[n] @ W1[0:128])[j]    + b1[j]/2   (src half)
//   half=1: P[n][64+j] = (Z[n] @ W1[128:256])[j]  + b1[j]/2   (dst half)
// P stored bf16 [n][128]. LDS = this half's W (128k x 64j fp32 = 32 KB).
// Thread tile 8 nodes x 8 cols (64 compile-time-indexed accs). tj=t&7 ->
// j0=8*tj (lanes tj, tj+4 overlap banks exactly -> 2-way = free). tn=t>>3
// -> 8 nodes each -> 256 nodes/block-iter. 32KB LDS -> ~4 blocks/CU.
// ---------------------------------------------------------------------------
__global__ __launch_bounds__(256, 2)
void node_proj_kernel(const float* __restrict__ Z, const float* __restrict__ W1,
                      const float* __restrict__ b1, ushort* __restrict__ P,
                      int n_nodes) {
    const int half = blockIdx.x & 1;           // 0 = src proj, 1 = dst proj
    const int bx   = blockIdx.x >> 1;
    const int nblk = gridDim.x >> 1;

    __shared__ float w1s[EMBED * HID];         // 32 KB
    const float* wsrc = W1 + half * EMBED * HID;
    for (int idx = threadIdx.x; idx < EMBED * HID; idx += 256)
        w1s[idx] = wsrc[idx];

    const int tj = threadIdx.x & 7;
    const int tn = threadIdx.x >> 3;
    const int j0 = tj * 8;

    float bh[8];
#pragma unroll
    for (int c = 0; c < 8; ++c) bh[c] = 0.5f * b1[j0 + c];

    __syncthreads();

    for (int base = bx * 256; base < n_nodes; base += nblk * 256) {
        const int node0 = base + tn * 8;

        int off[8];
#pragma unroll
        for (int i = 0; i < 8; ++i) {
            const int n = node0 + i;
            off[i] = (n < n_nodes ? n : n_nodes - 1) * EMBED;  // clamp loads
        }

        float acc[8][8];
#pragma unroll
        for (int i = 0; i < 8; ++i)
#pragma unroll
            for (int c = 0; c < 8; ++c) acc[i][c] = 0.f;

#pragma unroll 2
        for (int k0 = 0; k0 < EMBED; k0 += 4) {
            float4 zv[8];
#pragma unroll
            for (int i = 0; i < 8; ++i)
                zv[i] = *(const float4*)(Z + off[i] + k0);

            float4 wv[4][2];
#pragma unroll
            for (int kk = 0; kk < 4; ++kk) {
                wv[kk][0] = *(const float4*)(&w1s[(k0 + kk) * HID + j0]);
                wv[kk][1] = *(const float4*)(&w1s[(k0 + kk) * HID + j0 + 4]);
            }

#pragma unroll
            for (int i = 0; i < 8; ++i) {
                const float zk0 = zv[i].x, zk1 = zv[i].y, zk2 = zv[i].z, zk3 = zv[i].w;
#pragma unroll
                for (int kk = 0; kk < 4; ++kk) {
                    const float z = (kk == 0) ? zk0 : (kk == 1) ? zk1 : (kk == 2) ? zk2 : zk3;
                    acc[i][0] = fmaf(z, wv[kk][0].x, acc[i][0]);
                    acc[i][1] = fmaf(z, wv[kk][0].y, acc[i][1]);
                    acc[i][2] = fmaf(z, wv[kk][0].z, acc[i][2]);
                    acc[i][3] = fmaf(z, wv[kk][0].w, acc[i][3]);
                    acc[i][4] = fmaf(z, wv[kk][1].x, acc[i][4]);
                    acc[i][5] = fmaf(z, wv[kk][1].y, acc[i][5]);
                    acc[i][6] = fmaf(z, wv[kk][1].z, acc[i][6]);
                    acc[i][7] = fmaf(z, wv[kk][1].w, acc[i][7]);
                }
            }
        }

#pragma unroll
        for (int i = 0; i < 8; ++i) {
            const int n = node0 + i;
            if (n < n_nodes) {
                ushort8 pk;
#pragma unroll
                for (int c = 0; c < 8; ++c) pk[c] = f2bf(acc[i][c] + bh[c]);
                *(ushort8*)(P + (size_t)n * 128 + half * HID + j0) = pk;
            }
        }
    }
}

// ---------------------------------------------------------------------------
// Kernel 2: per-edge MLP over bf16 P, b1 pre-folded. 8 lanes/edge; lane l
// owns h[8l:8l+8]: one 16B bf16x8 gather per side. shfl_xor tree over 8.
//   out[e] = b2 + sum_j relu(P[s][j] + P[d][64+j]) * W2[j]
// ---------------------------------------------------------------------------
__global__ __launch_bounds__(256)
void edge_mlp_kernel(const ushort* __restrict__ P, const int* __restrict__ src,
                     const int* __restrict__ dst, const float* __restrict__ W2,
                     const float* __restrict__ b2, float* __restrict__ out,
                     int n_edges) {
    const int gtid  = blockIdx.x * 256 + threadIdx.x;
    const int lane8 = gtid & 7;
    const int e     = gtid >> 3;
    if (e >= n_edges) return;

    const float4 w2a = *(const float4*)(W2 + lane8 * 8);
    const float4 w2b = *(const float4*)(W2 + lane8 * 8 + 4);

    const int s = src[e];
    const int d = dst[e];
    const ushort8 ps = *(const ushort8*)(P + (size_t)s * 128 + lane8 * 8);
    const ushort8 pd = *(const ushort8*)(P + (size_t)d * 128 + HID + lane8 * 8);

    float part;
    {
        const float h0 = fmaxf(bf2f(ps[0]) + bf2f(pd[0]), 0.f);
        const float h1 = fmaxf(bf2f(ps[1]) + bf2f(pd[1]), 0.f);
        const float h2 = fmaxf(bf2f(ps[2]) + bf2f(pd[2]), 0.f);
        const float h3 = fmaxf(bf2f(ps[3]) + bf2f(pd[3]), 0.f);
        const float h4 = fmaxf(bf2f(ps[4]) + bf2f(pd[4]), 0.f);
        const float h5 = fmaxf(bf2f(ps[5]) + bf2f(pd[5]), 0.f);
        const float h6 = fmaxf(bf2f(ps[6]) + bf2f(pd[6]), 0.f);
        const float h7 = fmaxf(bf2f(ps[7]) + bf2f(pd[7]), 0.f);
        part = h0 * w2a.x + h1 * w2a.y + h2 * w2a.z + h3 * w2a.w
             + h4 * w2b.x + h5 * w2b.y + h6 * w2b.z + h7 * w2b.w;
    }

    part += __shfl_xor(part, 4, 8);
    part += __shfl_xor(part, 2, 8);
    part += __shfl_xor(part, 1, 8);

    if (lane8 == 0) out[e] = part + b2[0];
}

// ---------------------------------------------------------------------------
// FALLBACK (ws too small): workspace-free direct per-edge MLP, W1 in LDS.
// ---------------------------------------------------------------------------
__global__ __launch_bounds__(256)
void edge_direct_kernel(const float* __restrict__ Z, const int* __restrict__ src,
                        const int* __restrict__ dst, const float* __restrict__ W1,
                        const float* __restrict__ b1, const float* __restrict__ W2,
                        const float* __restrict__ b2, float* __restrict__ out,
                        int n_edges) {
    __shared__ float w1s[2 * EMBED * HID];   // 64 KB
    for (int i = threadIdx.x; i < 2 * EMBED * HID; i += 256) w1s[i] = W1[i];
    __syncthreads();

    const int gtid   = blockIdx.x * 256 + threadIdx.x;
    const int lane16 = gtid & 15;
    const int e      = gtid >> 4;
    if (e >= n_edges) return;

    const int s = src[e];
    const int d = dst[e];
    const float* zs = Z + (size_t)s * EMBED;
    const float* zd = Z + (size_t)d * EMBED;

    float h[4] = {b1[lane16 * 4 + 0], b1[lane16 * 4 + 1],
                  b1[lane16 * 4 + 2], b1[lane16 * 4 + 3]};
    for (int k = 0; k < EMBED; ++k) {
        const float zsk = zs[k];
        const float zdk = zd[k];
        const float4 w1a = *(const float4*)(&w1s[k * HID + lane16 * 4]);
        const float4 w1b = *(const float4*)(&w1s[(EMBED + k) * HID + lane16 * 4]);
        h[0] = fmaf(zsk, w1a.x, fmaf(zdk, w1b.x, h[0]));
        h[1] = fmaf(zsk, w1a.y, fmaf(zdk, w1b.y, h[1]));
        h[2] = fmaf(zsk, w1a.z, fmaf(zdk, w1b.z, h[2]));
        h[3] = fmaf(zsk, w1a.w, fmaf(zdk, w1b.w, h[3]));
    }

    const float4 w2v = *(const float4*)(W2 + lane16 * 4);
    float part = fmaxf(h[0], 0.f) * w2v.x + fmaxf(h[1], 0.f) * w2v.y +
                 fmaxf(h[2], 0.f) * w2v.z + fmaxf(h[3], 0.f) * w2v.w;
    part += __shfl_xor(part, 8, 16);
    part += __shfl_xor(part, 4, 16);
    part += __shfl_xor(part, 2, 16);
    part += __shfl_xor(part, 1, 16);

    if (lane16 == 0) out[e] = part + b2[0];
}

extern "C" void kernel_launch(void* const* d_in, const int* in_sizes, int n_in,
                              void* d_out, int out_size, void* d_ws, size_t ws_size,
                              hipStream_t stream) {
    const float* Z  = (const float*)d_in[0];
    const int*   EI = (const int*)d_in[1];   // [2, E]: src row then dst row
    const float* W1 = (const float*)d_in[2]; // [256, 64] row-major
    const float* b1 = (const float*)d_in[3]; // [64]
    const float* W2 = (const float*)d_in[4]; // [64]
    const float* b2 = (const float*)d_in[5]; // [1]
    float* out = (float*)d_out;

    const int n_nodes = in_sizes[0] / EMBED;
    const int E       = in_sizes[1] / 2;

    const size_t p_bytes = (size_t)n_nodes * (2 * HID) * sizeof(ushort);

    if (ws_size >= p_bytes) {
        ushort* P = (ushort*)d_ws;           // [n_nodes][128] bf16 = 25.6 MB
        const int node_blocks = 2 * ((n_nodes + 255) / 256);
        node_proj_kernel<<<node_blocks, 256, 0, stream>>>(Z, W1, b1, P, n_nodes);

        const int edge_blocks = (E * 8 + 255) / 256;
        edge_mlp_kernel<<<edge_blocks, 256, 0, stream>>>(
            P, EI, EI + E, W2, b2, out, E);
    } else {
        const int edge_blocks = (E * 16 + 255) / 256;
        edge_direct_kernel<<<edge_blocks, 256, 0, stream>>>(
            Z, EI, EI + E, W1, b1, W2, b2, out, E);
    }
}

// Round 6
// 175.772 us; speedup vs baseline: 1.1994x; 1.1994x over previous
//
#include <hip/hip_runtime.h>
#include <hip/hip_bf16.h>

#define EMBED 128   // node embedding dim
#define HID   64    // hidden dim

typedef unsigned short ushort;
typedef ushort ushort8 __attribute__((ext_vector_type(8)));

__device__ __forceinline__ float bf2f(ushort u) {
    union { unsigned int i; float f; } c;
    c.i = ((unsigned int)u) << 16;
    return c.f;
}
__device__ __forceinline__ ushort f2bf(float f) {
    union { float f; unsigned int i; } c;
    c.f = f;
    unsigned int r = c.i + 0x7FFFu + ((c.i >> 16) & 1u);   // RTNE
    return (ushort)(r >> 16);
}

// ---------------------------------------------------------------------------
// Kernel 1: node projection P[n][jj] = (Z[n] @ B2)[jj] + 0.5*b1[jj&63], bf16.
//   B2[k][jj] = jj<64 ? W1[k][jj] : W1[128+k][jj-64]  (src half | dst half)
// One block = 128 nodes x all 128 outputs (Z read ONCE from HBM).
// LDS: B2 fp32 64 KB + Z-tile [128n][32k] 16 KB = 80 KB -> 2 blocks/CU.
// Staging: wave reads 8 rows x 128 B contiguous aligned chunks (each L2 line
// fetched exactly once). Z-tile cols XOR-swizzled by 8*((row>>3)&3) so the
// 4-rowgroup z scalar reads are conflict-free. Thread tile 8n x 8j.
// ---------------------------------------------------------------------------
__global__ __launch_bounds__(256, 2)
void node_proj_kernel(const float* __restrict__ Z, const float* __restrict__ W1,
                      const float* __restrict__ b1, ushort* __restrict__ P,
                      int n_nodes) {
    __shared__ float w2s[128 * 128];   // B2, 64 KB
    __shared__ float zt[128 * 32];     // Z k-chunk tile, 16 KB

    const int t = threadIdx.x;

    // Stage B2 (one-time, coalesced 256B runs).
    for (int idx = t; idx < 128 * 128; idx += 256) {
        const int k = idx >> 7, jj = idx & 127;
        w2s[idx] = (jj < HID) ? W1[k * HID + jj]
                              : W1[(EMBED + k) * HID + (jj - HID)];
    }

    const int tj = t & 15;        // j-group: j0 = 8*tj covers 0..127
    const int tn = t >> 4;        // node-group: rows tn*8 .. tn*8+7
    const int j0 = tj * 8;
    const int base = blockIdx.x * 128;
    const int myswz = 8 * (tn & 3);       // z-tile column swizzle for my rows

    float bh[8];
#pragma unroll
    for (int c = 0; c < 8; ++c) bh[c] = 0.5f * b1[(j0 + c) & (HID - 1)];

    // staging coords: row sr+32*s, 16B chunk sc (8 lanes cover one 128B row)
    const int sr = t >> 3;        // 0..31
    const int sc = t & 7;         // 0..7

    float acc[8][8];
#pragma unroll
    for (int i = 0; i < 8; ++i)
#pragma unroll
        for (int c = 0; c < 8; ++c) acc[i][c] = 0.f;

    for (int it = 0; it < 4; ++it) {
        const int k0 = it * 32;

        // ---- stage Z[base..base+127][k0..k0+31] into zt (coalesced) ----
#pragma unroll
        for (int s = 0; s < 4; ++s) {
            const int r = sr + 32 * s;
            int gn = base + r;
            if (gn >= n_nodes) gn = n_nodes - 1;          // clamp (writes guarded)
            const float4 g = *(const float4*)(Z + (size_t)gn * EMBED + k0 + sc * 4);
            const int pc = (sc * 4) ^ (8 * ((r >> 3) & 3));
            *(float4*)(&zt[r * 32 + pc]) = g;
        }
        __syncthreads();

        // ---- compute this k-chunk ----
#pragma unroll 2
        for (int k = 0; k < 32; ++k) {
            const float4 wv0 = *(const float4*)(&w2s[(k0 + k) * 128 + j0]);
            const float4 wv1 = *(const float4*)(&w2s[(k0 + k) * 128 + j0 + 4]);
            const int zc = k ^ myswz;
            float zv[8];
#pragma unroll
            for (int i = 0; i < 8; ++i)
                zv[i] = zt[(tn * 8 + i) * 32 + zc];
#pragma unroll
            for (int i = 0; i < 8; ++i) {
                acc[i][0] = fmaf(zv[i], wv0.x, acc[i][0]);
                acc[i][1] = fmaf(zv[i], wv0.y, acc[i][1]);
                acc[i][2] = fmaf(zv[i], wv0.z, acc[i][2]);
                acc[i][3] = fmaf(zv[i], wv0.w, acc[i][3]);
                acc[i][4] = fmaf(zv[i], wv1.x, acc[i][4]);
                acc[i][5] = fmaf(zv[i], wv1.y, acc[i][5]);
                acc[i][6] = fmaf(zv[i], wv1.z, acc[i][6]);
                acc[i][7] = fmaf(zv[i], wv1.w, acc[i][7]);
            }
        }
        __syncthreads();    // zt reused next chunk
    }

    // ---- epilogue: bf16 pack + store (ushort8 = 16B per thread) ----
#pragma unroll
    for (int i = 0; i < 8; ++i) {
        const int n = base + tn * 8 + i;
        if (n < n_nodes) {
            ushort8 pk;
#pragma unroll
            for (int c = 0; c < 8; ++c) pk[c] = f2bf(acc[i][c] + bh[c]);
            *(ushort8*)(P + (size_t)n * 128 + j0) = pk;
        }
    }
}

// ---------------------------------------------------------------------------
// Kernel 2: per-edge MLP over bf16 P, b1 pre-folded. 8 lanes/edge; lane l
// owns h[8l:8l+8]: one 16B bf16x8 gather per side. shfl_xor tree over 8.
//   out[e] = b2 + sum_j relu(P[s][j] + P[d][64+j]) * W2[j]
// ---------------------------------------------------------------------------
__global__ __launch_bounds__(256)
void edge_mlp_kernel(const ushort* __restrict__ P, const int* __restrict__ src,
                     const int* __restrict__ dst, const float* __restrict__ W2,
                     const float* __restrict__ b2, float* __restrict__ out,
                     int n_edges) {
    const int gtid  = blockIdx.x * 256 + threadIdx.x;
    const int lane8 = gtid & 7;
    const int e     = gtid >> 3;
    if (e >= n_edges) return;

    const float4 w2a = *(const float4*)(W2 + lane8 * 8);
    const float4 w2b = *(const float4*)(W2 + lane8 * 8 + 4);

    const int s = src[e];
    const int d = dst[e];
    const ushort8 ps = *(const ushort8*)(P + (size_t)s * 128 + lane8 * 8);
    const ushort8 pd = *(const ushort8*)(P + (size_t)d * 128 + HID + lane8 * 8);

    float part;
    {
        const float h0 = fmaxf(bf2f(ps[0]) + bf2f(pd[0]), 0.f);
        const float h1 = fmaxf(bf2f(ps[1]) + bf2f(pd[1]), 0.f);
        const float h2 = fmaxf(bf2f(ps[2]) + bf2f(pd[2]), 0.f);
        const float h3 = fmaxf(bf2f(ps[3]) + bf2f(pd[3]), 0.f);
        const float h4 = fmaxf(bf2f(ps[4]) + bf2f(pd[4]), 0.f);
        const float h5 = fmaxf(bf2f(ps[5]) + bf2f(pd[5]), 0.f);
        const float h6 = fmaxf(bf2f(ps[6]) + bf2f(pd[6]), 0.f);
        const float h7 = fmaxf(bf2f(ps[7]) + bf2f(pd[7]), 0.f);
        part = h0 * w2a.x + h1 * w2a.y + h2 * w2a.z + h3 * w2a.w
             + h4 * w2b.x + h5 * w2b.y + h6 * w2b.z + h7 * w2b.w;
    }

    part += __shfl_xor(part, 4, 8);
    part += __shfl_xor(part, 2, 8);
    part += __shfl_xor(part, 1, 8);

    if (lane8 == 0) out[e] = part + b2[0];
}

// ---------------------------------------------------------------------------
// FALLBACK (ws too small): workspace-free direct per-edge MLP, W1 in LDS.
// ---------------------------------------------------------------------------
__global__ __launch_bounds__(256)
void edge_direct_kernel(const float* __restrict__ Z, const int* __restrict__ src,
                        const int* __restrict__ dst, const float* __restrict__ W1,
                        const float* __restrict__ b1, const float* __restrict__ W2,
                        const float* __restrict__ b2, float* __restrict__ out,
                        int n_edges) {
    __shared__ float w1s[2 * EMBED * HID];   // 64 KB
    for (int i = threadIdx.x; i < 2 * EMBED * HID; i += 256) w1s[i] = W1[i];
    __syncthreads();

    const int gtid   = blockIdx.x * 256 + threadIdx.x;
    const int lane16 = gtid & 15;
    const int e      = gtid >> 4;
    if (e >= n_edges) return;

    const int s = src[e];
    const int d = dst[e];
    const float* zs = Z + (size_t)s * EMBED;
    const float* zd = Z + (size_t)d * EMBED;

    float h[4] = {b1[lane16 * 4 + 0], b1[lane16 * 4 + 1],
                  b1[lane16 * 4 + 2], b1[lane16 * 4 + 3]};
    for (int k = 0; k < EMBED; ++k) {
        const float zsk = zs[k];
        const float zdk = zd[k];
        const float4 w1a = *(const float4*)(&w1s[k * HID + lane16 * 4]);
        const float4 w1b = *(const float4*)(&w1s[(EMBED + k) * HID + lane16 * 4]);
        h[0] = fmaf(zsk, w1a.x, fmaf(zdk, w1b.x, h[0]));
        h[1] = fmaf(zsk, w1a.y, fmaf(zdk, w1b.y, h[1]));
        h[2] = fmaf(zsk, w1a.z, fmaf(zdk, w1b.z, h[2]));
        h[3] = fmaf(zsk, w1a.w, fmaf(zdk, w1b.w, h[3]));
    }

    const float4 w2v = *(const float4*)(W2 + lane16 * 4);
    float part = fmaxf(h[0], 0.f) * w2v.x + fmaxf(h[1], 0.f) * w2v.y +
                 fmaxf(h[2], 0.f) * w2v.z + fmaxf(h[3], 0.f) * w2v.w;
    part += __shfl_xor(part, 8, 16);
    part += __shfl_xor(part, 4, 16);
    part += __shfl_xor(part, 2, 16);
    part += __shfl_xor(part, 1, 16);

    if (lane16 == 0) out[e] = part + b2[0];
}

extern "C" void kernel_launch(void* const* d_in, const int* in_sizes, int n_in,
                              void* d_out, int out_size, void* d_ws, size_t ws_size,
                              hipStream_t stream) {
    const float* Z  = (const float*)d_in[0];
    const int*   EI = (const int*)d_in[1];   // [2, E]: src row then dst row
    const float* W1 = (const float*)d_in[2]; // [256, 64] row-major
    const float* b1 = (const float*)d_in[3]; // [64]
    const float* W2 = (const float*)d_in[4]; // [64]
    const float* b2 = (const float*)d_in[5]; // [1]
    float* out = (float*)d_out;

    const int n_nodes = in_sizes[0] / EMBED;
    const int E       = in_sizes[1] / 2;

    const size_t p_bytes = (size_t)n_nodes * (2 * HID) * sizeof(ushort);

    if (ws_size >= p_bytes) {
        ushort* P = (ushort*)d_ws;           // [n_nodes][128] bf16 = 25.6 MB
        const int node_blocks = (n_nodes + 127) / 128;
        node_proj_kernel<<<node_blocks, 256, 0, stream>>>(Z, W1, b1, P, n_nodes);

        const int edge_blocks = (E * 8 + 255) / 256;
        edge_mlp_kernel<<<edge_blocks, 256, 0, stream>>>(
            P, EI, EI + E, W2, b2, out, E);
    } else {
        const int edge_blocks = (E * 16 + 255) / 256;
        edge_direct_kernel<<<edge_blocks, 256, 0, stream>>>(
            Z, EI, EI + E, W1, b1, W2, b2, out, E);
    }
}

// Round 7
// 174.860 us; speedup vs baseline: 1.2056x; 1.0052x over previous
//
#include <hip/hip_runtime.h>
#include <hip/hip_bf16.h>

#define EMBED 128   // node embedding dim
#define HID   64    // hidden dim

typedef unsigned short ushort;
typedef ushort ushort8 __attribute__((ext_vector_type(8)));
typedef ushort ushort4_t __attribute__((ext_vector_type(4)));

__device__ __forceinline__ float bf2f(ushort u) {
    union { unsigned int i; float f; } c;
    c.i = ((unsigned int)u) << 16;
    return c.f;
}
__device__ __forceinline__ ushort f2bf(float f) {
    union { float f; unsigned int i; } c;
    c.f = f;
    unsigned int r = c.i + 0x7FFFu + ((c.i >> 16) & 1u);   // RTNE
    return (ushort)(r >> 16);
}

// ---------------------------------------------------------------------------
// Kernel 1: node projection P[n][jj] = (Z[n] @ B2)[jj] + 0.5*b1[jj&63], bf16.
//   B2[k][jj] = jj<64 ? W1[k][jj] : W1[128+k][jj-64]
// One block = 128 nodes x all 128 outputs (Z fetched exactly once from HBM).
// LDS: B2 fp32 64 KB + zt[32k][128n] fp32 16 KB (TRANSPOSED, col XOR-swizzled
// by 8*((k>>2)&3)) = 80 KB -> 2 blocks/CU.
// Thread (tj=t&15, tn=t>>4) owns cols {4tj..4tj+3, 64+4tj..64+4tj+3} x nodes
// {8tn..8tn+7}. Per k: 2 b128 w-reads (banks 2-way=free) + 2 b128 z-reads
// (broadcast across tj, conflict-free across tn) + 64 FMA. No scalar LDS ops.
// ---------------------------------------------------------------------------
__global__ __launch_bounds__(256, 2)
void node_proj_kernel(const float* __restrict__ Z, const float* __restrict__ W1,
                      const float* __restrict__ b1, ushort* __restrict__ P,
                      int n_nodes) {
    __shared__ float w2s[128 * 128];   // B2, 64 KB
    __shared__ float zt[32 * 128];     // transposed Z k-chunk tile, 16 KB

    const int t = threadIdx.x;

    // Stage B2 (one-time, coalesced).
    for (int idx = t; idx < 128 * 128; idx += 256) {
        const int k = idx >> 7, jj = idx & 127;
        w2s[idx] = (jj < HID) ? W1[k * HID + jj]
                              : W1[(EMBED + k) * HID + (jj - HID)];
    }

    const int tj = t & 15;        // col group: jA=4tj, jB=64+4tj
    const int tn = t >> 4;        // node group: rows 8tn..8tn+7
    const int jA = tj * 4;
    const int base = blockIdx.x * 128;

    float bh[4];
#pragma unroll
    for (int c = 0; c < 4; ++c) bh[c] = 0.5f * b1[jA + c];

    // staging coords: thread loads Z rows r=sr+32s, cols k0+4sc..+3
    const int sr = t >> 3;        // 0..31
    const int sc = t & 7;         // 0..7
    const int wswz = 8 * (sc & 3);         // write-side column swizzle

    float acc[8][8];
#pragma unroll
    for (int i = 0; i < 8; ++i)
#pragma unroll
        for (int c = 0; c < 8; ++c) acc[i][c] = 0.f;

    for (int it = 0; it < 4; ++it) {
        const int k0 = it * 32;

        // ---- stage Z[base+r][k0+4sc+q] -> zt[4sc+q][r ^ 8*(sc&3)] ----
#pragma unroll
        for (int s = 0; s < 4; ++s) {
            const int r = sr + 32 * s;
            int gn = base + r;
            if (gn >= n_nodes) gn = n_nodes - 1;          // clamp (stores guarded)
            const float4 g = *(const float4*)(Z + (size_t)gn * EMBED + k0 + sc * 4);
            const int col = r ^ wswz;
            zt[(sc * 4 + 0) * 128 + col] = g.x;
            zt[(sc * 4 + 1) * 128 + col] = g.y;
            zt[(sc * 4 + 2) * 128 + col] = g.z;
            zt[(sc * 4 + 3) * 128 + col] = g.w;
        }
        __syncthreads();

        // ---- compute this k-chunk ----
#pragma unroll 4
        for (int k = 0; k < 32; ++k) {
            const float4 wv0 = *(const float4*)(&w2s[(k0 + k) * 128 + jA]);
            const float4 wv1 = *(const float4*)(&w2s[(k0 + k) * 128 + 64 + jA]);
            const int zb = 8 * (tn ^ ((k >> 2) & 3));
            const float4 z0 = *(const float4*)(&zt[k * 128 + zb]);
            const float4 z1 = *(const float4*)(&zt[k * 128 + zb + 4]);

#pragma unroll
            for (int i = 0; i < 4; ++i) {
                const float zi = (i == 0) ? z0.x : (i == 1) ? z0.y : (i == 2) ? z0.z : z0.w;
                acc[i][0] = fmaf(zi, wv0.x, acc[i][0]);
                acc[i][1] = fmaf(zi, wv0.y, acc[i][1]);
                acc[i][2] = fmaf(zi, wv0.z, acc[i][2]);
                acc[i][3] = fmaf(zi, wv0.w, acc[i][3]);
                acc[i][4] = fmaf(zi, wv1.x, acc[i][4]);
                acc[i][5] = fmaf(zi, wv1.y, acc[i][5]);
                acc[i][6] = fmaf(zi, wv1.z, acc[i][6]);
                acc[i][7] = fmaf(zi, wv1.w, acc[i][7]);
            }
#pragma unroll
            for (int i = 4; i < 8; ++i) {
                const float zi = (i == 4) ? z1.x : (i == 5) ? z1.y : (i == 6) ? z1.z : z1.w;
                acc[i][0] = fmaf(zi, wv0.x, acc[i][0]);
                acc[i][1] = fmaf(zi, wv0.y, acc[i][1]);
                acc[i][2] = fmaf(zi, wv0.z, acc[i][2]);
                acc[i][3] = fmaf(zi, wv0.w, acc[i][3]);
                acc[i][4] = fmaf(zi, wv1.x, acc[i][4]);
                acc[i][5] = fmaf(zi, wv1.y, acc[i][5]);
                acc[i][6] = fmaf(zi, wv1.z, acc[i][6]);
                acc[i][7] = fmaf(zi, wv1.w, acc[i][7]);
            }
        }
        __syncthreads();    // zt reused next chunk
    }

    // ---- epilogue: bf16 pack + two 8B stores per node ----
#pragma unroll
    for (int i = 0; i < 8; ++i) {
        const int n = base + tn * 8 + i;
        if (n < n_nodes) {
            ushort4_t pa, pb;
#pragma unroll
            for (int c = 0; c < 4; ++c) {
                pa[c] = f2bf(acc[i][c] + bh[c]);
                pb[c] = f2bf(acc[i][c + 4] + bh[c]);
            }
            *(ushort4_t*)(P + (size_t)n * 128 + jA)      = pa;
            *(ushort4_t*)(P + (size_t)n * 128 + 64 + jA) = pb;
        }
    }
}

// ---------------------------------------------------------------------------
// Kernel 2: per-edge MLP over bf16 P, b1 pre-folded. 8 lanes/edge-slot, 4
// edges per thread (quarter-split: e_m = g + m*quarter, coalesced index
// loads, 8 independent 16B gathers in flight). shfl_xor tree over 8 lanes.
//   out[e] = b2 + sum_j relu(P[s][j] + P[d][64+j]) * W2[j]
// ---------------------------------------------------------------------------
__global__ __launch_bounds__(256)
void edge_mlp_kernel(const ushort* __restrict__ P, const int* __restrict__ src,
                     const int* __restrict__ dst, const float* __restrict__ W2,
                     const float* __restrict__ b2, float* __restrict__ out,
                     int n_edges) {
    const int gtid  = blockIdx.x * 256 + threadIdx.x;
    const int lane8 = gtid & 7;
    const int g     = gtid >> 3;
    const int quarter = (n_edges + 3) >> 2;
    if (g >= quarter) return;

    const float4 w2a = *(const float4*)(W2 + lane8 * 8);
    const float4 w2b = *(const float4*)(W2 + lane8 * 8 + 4);

    int e[4];  bool ok[4];
    int s[4], d[4];
#pragma unroll
    for (int m = 0; m < 4; ++m) {
        e[m] = g + m * quarter;
        ok[m] = e[m] < n_edges;
        const int ec = ok[m] ? e[m] : 0;
        s[m] = src[ec];
        d[m] = dst[ec];
    }

    ushort8 ps[4], pd[4];
#pragma unroll
    for (int m = 0; m < 4; ++m) {
        ps[m] = *(const ushort8*)(P + (size_t)s[m] * 128 + lane8 * 8);
        pd[m] = *(const ushort8*)(P + (size_t)d[m] * 128 + HID + lane8 * 8);
    }

    float part[4];
#pragma unroll
    for (int m = 0; m < 4; ++m) {
        const float h0 = fmaxf(bf2f(ps[m][0]) + bf2f(pd[m][0]), 0.f);
        const float h1 = fmaxf(bf2f(ps[m][1]) + bf2f(pd[m][1]), 0.f);
        const float h2 = fmaxf(bf2f(ps[m][2]) + bf2f(pd[m][2]), 0.f);
        const float h3 = fmaxf(bf2f(ps[m][3]) + bf2f(pd[m][3]), 0.f);
        const float h4 = fmaxf(bf2f(ps[m][4]) + bf2f(pd[m][4]), 0.f);
        const float h5 = fmaxf(bf2f(ps[m][5]) + bf2f(pd[m][5]), 0.f);
        const float h6 = fmaxf(bf2f(ps[m][6]) + bf2f(pd[m][6]), 0.f);
        const float h7 = fmaxf(bf2f(ps[m][7]) + bf2f(pd[m][7]), 0.f);
        part[m] = h0 * w2a.x + h1 * w2a.y + h2 * w2a.z + h3 * w2a.w
                + h4 * w2b.x + h5 * w2b.y + h6 * w2b.z + h7 * w2b.w;
    }

#pragma unroll
    for (int m = 0; m < 4; ++m) {
        part[m] += __shfl_xor(part[m], 4, 8);
        part[m] += __shfl_xor(part[m], 2, 8);
        part[m] += __shfl_xor(part[m], 1, 8);
    }

    if (lane8 == 0) {
        const float bb = b2[0];
#pragma unroll
        for (int m = 0; m < 4; ++m)
            if (ok[m]) out[e[m]] = part[m] + bb;
    }
}

// ---------------------------------------------------------------------------
// FALLBACK (ws too small): workspace-free direct per-edge MLP, W1 in LDS.
// ---------------------------------------------------------------------------
__global__ __launch_bounds__(256)
void edge_direct_kernel(const float* __restrict__ Z, const int* __restrict__ src,
                        const int* __restrict__ dst, const float* __restrict__ W1,
                        const float* __restrict__ b1, const float* __restrict__ W2,
                        const float* __restrict__ b2, float* __restrict__ out,
                        int n_edges) {
    __shared__ float w1s[2 * EMBED * HID];   // 64 KB
    for (int i = threadIdx.x; i < 2 * EMBED * HID; i += 256) w1s[i] = W1[i];
    __syncthreads();

    const int gtid   = blockIdx.x * 256 + threadIdx.x;
    const int lane16 = gtid & 15;
    const int e      = gtid >> 4;
    if (e >= n_edges) return;

    const int s = src[e];
    const int d = dst[e];
    const float* zs = Z + (size_t)s * EMBED;
    const float* zd = Z + (size_t)d * EMBED;

    float h[4] = {b1[lane16 * 4 + 0], b1[lane16 * 4 + 1],
                  b1[lane16 * 4 + 2], b1[lane16 * 4 + 3]};
    for (int k = 0; k < EMBED; ++k) {
        const float zsk = zs[k];
        const float zdk = zd[k];
        const float4 w1a = *(const float4*)(&w1s[k * HID + lane16 * 4]);
        const float4 w1b = *(const float4*)(&w1s[(EMBED + k) * HID + lane16 * 4]);
        h[0] = fmaf(zsk, w1a.x, fmaf(zdk, w1b.x, h[0]));
        h[1] = fmaf(zsk, w1a.y, fmaf(zdk, w1b.y, h[1]));
        h[2] = fmaf(zsk, w1a.z, fmaf(zdk, w1b.z, h[2]));
        h[3] = fmaf(zsk, w1a.w, fmaf(zdk, w1b.w, h[3]));
    }

    const float4 w2v = *(const float4*)(W2 + lane16 * 4);
    float part = fmaxf(h[0], 0.f) * w2v.x + fmaxf(h[1], 0.f) * w2v.y +
                 fmaxf(h[2], 0.f) * w2v.z + fmaxf(h[3], 0.f) * w2v.w;
    part += __shfl_xor(part, 8, 16);
    part += __shfl_xor(part, 4, 16);
    part += __shfl_xor(part, 2, 16);
    part += __shfl_xor(part, 1, 16);

    if (lane16 == 0) out[e] = part + b2[0];
}

extern "C" void kernel_launch(void* const* d_in, const int* in_sizes, int n_in,
                              void* d_out, int out_size, void* d_ws, size_t ws_size,
                              hipStream_t stream) {
    const float* Z  = (const float*)d_in[0];
    const int*   EI = (const int*)d_in[1];   // [2, E]: src row then dst row
    const float* W1 = (const float*)d_in[2]; // [256, 64] row-major
    const float* b1 = (const float*)d_in[3]; // [64]
    const float* W2 = (const float*)d_in[4]; // [64]
    const float* b2 = (const float*)d_in[5]; // [1]
    float* out = (float*)d_out;

    const int n_nodes = in_sizes[0] / EMBED;
    const int E       = in_sizes[1] / 2;

    const size_t p_bytes = (size_t)n_nodes * (2 * HID) * sizeof(ushort);

    if (ws_size >= p_bytes) {
        ushort* P = (ushort*)d_ws;           // [n_nodes][128] bf16 = 25.6 MB
        const int node_blocks = (n_nodes + 127) / 128;
        node_proj_kernel<<<node_blocks, 256, 0, stream>>>(Z, W1, b1, P, n_nodes);

        const int quarter = (E + 3) >> 2;
        const int edge_blocks = (quarter * 8 + 255) / 256;
        edge_mlp_kernel<<<edge_blocks, 256, 0, stream>>>(
            P, EI, EI + E, W2, b2, out, E);
    } else {
        const int edge_blocks = (E * 16 + 255) / 256;
        edge_direct_kernel<<<edge_blocks, 256, 0, stream>>>(
            Z, EI, EI + E, W1, b1, W2, b2, out, E);
    }
}

// Round 9
// 141.804 us; speedup vs baseline: 1.4867x; 1.2331x over previous
//
#include <hip/hip_runtime.h>
#include <hip/hip_bf16.h>

#define EMBED 128   // node embedding dim
#define HID   64    // hidden dim

typedef unsigned short ushort;
typedef ushort ushort8 __attribute__((ext_vector_type(8)));
typedef short  bf16x8  __attribute__((ext_vector_type(8)));   // 8 bf16 = 4 VGPR
typedef float  f32x4   __attribute__((ext_vector_type(4)));

__device__ __forceinline__ float bf2f(ushort u) {
    union { unsigned int i; float f; } c;
    c.i = ((unsigned int)u) << 16;
    return c.f;
}
__device__ __forceinline__ ushort f2bf(float f) {
    union { float f; unsigned int i; } c;
    c.f = f;
    unsigned int r = c.i + 0x7FFFu + ((c.i >> 16) & 1u);   // RTNE
    return (ushort)(r >> 16);
}

// ---------------------------------------------------------------------------
// frag_prep: write B2 = [W1-src-half | W1-dst-half] as MFMA B-fragments in
// exact per-lane order, split hi/lo bf16 (compensated: hi+lo ~= fp32).
// Frag (jt,kt): lane l, reg r holds B2[k = kt*32 + 8*(l>>4) + r][jt*16 + (l&15)].
// Layout: frag[(jt*4+kt)*64*8 + lane*8 + r] -> a wave's ds_read_b128 at
// lane-contiguous 16B is the canonical conflict-free pattern.
// 2048 threads: one per (jt,kt,lane).
// ---------------------------------------------------------------------------
__global__ __launch_bounds__(256)
void frag_prep_kernel(const float* __restrict__ W1, ushort* __restrict__ fragH,
                      ushort* __restrict__ fragL) {
    const int tid = blockIdx.x * 256 + threadIdx.x;
    if (tid >= 2048) return;
    const int lane = tid & 63;
    const int kt   = (tid >> 6) & 3;
    const int jt   = tid >> 8;          // 0..7
    const int q    = lane >> 4;
    const int m16  = lane & 15;

    ushort8 fh, fl;
#pragma unroll
    for (int r = 0; r < 8; ++r) {
        const int k = kt * 32 + q * 8 + r;
        const int j = jt * 16 + m16;
        const float v = (j < HID) ? W1[k * HID + j]
                                  : W1[(EMBED + k) * HID + (j - HID)];
        const ushort h = f2bf(v);
        fh[r] = h;
        fl[r] = f2bf(v - bf2f(h));
    }
    const int fi = (jt * 4 + kt) * 64 + lane;
    *(ushort8*)(fragH + fi * 8) = fh;
    *(ushort8*)(fragL + fi * 8) = fl;
}

// ---------------------------------------------------------------------------
// node_proj_mfma: P[n][jj] = (Z[n] @ B2)[jj] + 0.5*b1[jj&63], stored bf16.
// Split-bf16 MFMA: acc += Ah*Bh + Al*Bh + Ah*Bl (error ~2^-18, fp32-like).
// Block 256 = 4 waves; wave owns 32 nodes (two 16-row A-tiles) x 128 cols
// (8 j-tiles). LDS: staged B-frags hi+lo = 64 KB -> 2 blocks/CU.
// Z loads: lane reads rows n0+(l&15), n0+16+(l&15), 32B at k=kt*32+8*(l>>4)
// -> 4 lanes cover each 128B line exactly once.
// D layout (m89): col = lane&15, row = (lane>>4)*4 + reg.
// ---------------------------------------------------------------------------
__global__ __launch_bounds__(256, 2)
void node_proj_mfma(const float* __restrict__ Z, const ushort* __restrict__ fragH,
                    const ushort* __restrict__ fragL, const float* __restrict__ b1,
                    ushort* __restrict__ P, int n_nodes) {
    __shared__ __align__(16) ushort sFH[32 * 64 * 8];   // 32 KB
    __shared__ __align__(16) ushort sFL[32 * 64 * 8];   // 32 KB

    const int t = threadIdx.x;

    // stage frags (coalesced 16B copies; L2-hot after first blocks)
    for (int i = t; i < 2048; i += 256) {
        ((ushort8*)sFH)[i] = ((const ushort8*)fragH)[i];
        ((ushort8*)sFL)[i] = ((const ushort8*)fragL)[i];
    }

    const int wave = t >> 6;
    const int lane = t & 63;
    const int q    = lane >> 4;       // k-group
    const int m16  = lane & 15;
    const int n0   = blockIdx.x * 128 + wave * 32;

    const int rA = n0 + m16;
    const int rB = n0 + 16 + m16;
    const float* gA = Z + (size_t)(rA < n_nodes ? rA : n_nodes - 1) * EMBED;
    const float* gB = Z + (size_t)(rB < n_nodes ? rB : n_nodes - 1) * EMBED;

    float b1h[4];
#pragma unroll
    for (int jm = 0; jm < 4; ++jm) b1h[jm] = 0.5f * b1[jm * 16 + m16];

    __syncthreads();

    f32x4 acc0[8], acc1[8];
#pragma unroll
    for (int jt = 0; jt < 8; ++jt) {
        acc0[jt] = (f32x4){0.f, 0.f, 0.f, 0.f};
        acc1[jt] = (f32x4){0.f, 0.f, 0.f, 0.f};
    }

    for (int kt = 0; kt < 4; ++kt) {
        const int k0 = kt * 32 + q * 8;

        float za[8], zb[8];
        *(float4*)(za)     = *(const float4*)(gA + k0);
        *(float4*)(za + 4) = *(const float4*)(gA + k0 + 4);
        *(float4*)(zb)     = *(const float4*)(gB + k0);
        *(float4*)(zb + 4) = *(const float4*)(gB + k0 + 4);

        bf16x8 ah0, al0, ah1, al1;
#pragma unroll
        for (int r = 0; r < 8; ++r) {
            const ushort h0 = f2bf(za[r]);
            ah0[r] = (short)h0;
            al0[r] = (short)f2bf(za[r] - bf2f(h0));
            const ushort h1 = f2bf(zb[r]);
            ah1[r] = (short)h1;
            al1[r] = (short)f2bf(zb[r] - bf2f(h1));
        }

#pragma unroll
        for (int jt = 0; jt < 8; ++jt) {
            const int fi = (jt * 4 + kt) * 64 + lane;
            const bf16x8 bh = ((const bf16x8*)sFH)[fi];
            const bf16x8 bl = ((const bf16x8*)sFL)[fi];

            acc0[jt] = __builtin_amdgcn_mfma_f32_16x16x32_bf16(ah0, bh, acc0[jt], 0, 0, 0);
            acc0[jt] = __builtin_amdgcn_mfma_f32_16x16x32_bf16(al0, bh, acc0[jt], 0, 0, 0);
            acc0[jt] = __builtin_amdgcn_mfma_f32_16x16x32_bf16(ah0, bl, acc0[jt], 0, 0, 0);

            acc1[jt] = __builtin_amdgcn_mfma_f32_16x16x32_bf16(ah1, bh, acc1[jt], 0, 0, 0);
            acc1[jt] = __builtin_amdgcn_mfma_f32_16x16x32_bf16(al1, bh, acc1[jt], 0, 0, 0);
            acc1[jt] = __builtin_amdgcn_mfma_f32_16x16x32_bf16(ah1, bl, acc1[jt], 0, 0, 0);
        }
    }

    // epilogue: D row = (lane>>4)*4 + reg, col = jt*16 + (lane&15)
#pragma unroll
    for (int jt = 0; jt < 8; ++jt) {
        const int col = jt * 16 + m16;
        const float bb = b1h[jt & 3];
#pragma unroll
        for (int r = 0; r < 4; ++r) {
            const int ra = n0 + q * 4 + r;
            if (ra < n_nodes) P[(size_t)ra * 128 + col] = f2bf(acc0[jt][r] + bb);
            const int rb = n0 + 16 + q * 4 + r;
            if (rb < n_nodes) P[(size_t)rb * 128 + col] = f2bf(acc1[jt][r] + bb);
        }
    }
}

// ---------------------------------------------------------------------------
// Kernel 2: per-edge MLP over bf16 P, b1 pre-folded. 8 lanes/edge; lane l
// owns h[8l:8l+8]: one 16B bf16x8 gather per side. shfl_xor tree over 8.
//   out[e] = b2 + sum_j relu(P[s][j] + P[d][64+j]) * W2[j]
// ---------------------------------------------------------------------------
__global__ __launch_bounds__(256)
void edge_mlp_kernel(const ushort* __restrict__ P, const int* __restrict__ src,
                     const int* __restrict__ dst, const float* __restrict__ W2,
                     const float* __restrict__ b2, float* __restrict__ out,
                     int n_edges) {
    const int gtid  = blockIdx.x * 256 + threadIdx.x;
    const int lane8 = gtid & 7;
    const int e     = gtid >> 3;
    if (e >= n_edges) return;

    const float4 w2a = *(const float4*)(W2 + lane8 * 8);
    const float4 w2b = *(const float4*)(W2 + lane8 * 8 + 4);

    const int s = src[e];
    const int d = dst[e];
    const ushort8 ps = *(const ushort8*)(P + (size_t)s * 128 + lane8 * 8);
    const ushort8 pd = *(const ushort8*)(P + (size_t)d * 128 + HID + lane8 * 8);

    float part;
    {
        const float h0 = fmaxf(bf2f(ps[0]) + bf2f(pd[0]), 0.f);
        const float h1 = fmaxf(bf2f(ps[1]) + bf2f(pd[1]), 0.f);
        const float h2 = fmaxf(bf2f(ps[2]) + bf2f(pd[2]), 0.f);
        const float h3 = fmaxf(bf2f(ps[3]) + bf2f(pd[3]), 0.f);
        const float h4 = fmaxf(bf2f(ps[4]) + bf2f(pd[4]), 0.f);
        const float h5 = fmaxf(bf2f(ps[5]) + bf2f(pd[5]), 0.f);
        const float h6 = fmaxf(bf2f(ps[6]) + bf2f(pd[6]), 0.f);
        const float h7 = fmaxf(bf2f(ps[7]) + bf2f(pd[7]), 0.f);
        part = h0 * w2a.x + h1 * w2a.y + h2 * w2a.z + h3 * w2a.w
             + h4 * w2b.x + h5 * w2b.y + h6 * w2b.z + h7 * w2b.w;
    }

    part += __shfl_xor(part, 4, 8);
    part += __shfl_xor(part, 2, 8);
    part += __shfl_xor(part, 1, 8);

    if (lane8 == 0) out[e] = part + b2[0];
}

// ---------------------------------------------------------------------------
// FALLBACK (ws too small): workspace-free direct per-edge MLP, W1 in LDS.
// ---------------------------------------------------------------------------
__global__ __launch_bounds__(256)
void edge_direct_kernel(const float* __restrict__ Z, const int* __restrict__ src,
                        const int* __restrict__ dst, const float* __restrict__ W1,
                        const float* __restrict__ b1, const float* __restrict__ W2,
                        const float* __restrict__ b2, float* __restrict__ out,
                        int n_edges) {
    __shared__ float w1s[2 * EMBED * HID];   // 64 KB
    for (int i = threadIdx.x; i < 2 * EMBED * HID; i += 256) w1s[i] = W1[i];
    __syncthreads();

    const int gtid   = blockIdx.x * 256 + threadIdx.x;
    const int lane16 = gtid & 15;
    const int e      = gtid >> 4;
    if (e >= n_edges) return;

    const int s = src[e];
    const int d = dst[e];
    const float* zs = Z + (size_t)s * EMBED;
    const float* zd = Z + (size_t)d * EMBED;

    float h[4] = {b1[lane16 * 4 + 0], b1[lane16 * 4 + 1],
                  b1[lane16 * 4 + 2], b1[lane16 * 4 + 3]};
    for (int k = 0; k < EMBED; ++k) {
        const float zsk = zs[k];
        const float zdk = zd[k];
        const float4 w1a = *(const float4*)(&w1s[k * HID + lane16 * 4]);
        const float4 w1b = *(const float4*)(&w1s[(EMBED + k) * HID + lane16 * 4]);
        h[0] = fmaf(zsk, w1a.x, fmaf(zdk, w1b.x, h[0]));
        h[1] = fmaf(zsk, w1a.y, fmaf(zdk, w1b.y, h[1]));
        h[2] = fmaf(zsk, w1a.z, fmaf(zdk, w1b.z, h[2]));
        h[3] = fmaf(zsk, w1a.w, fmaf(zdk, w1b.w, h[3]));
    }

    const float4 w2v = *(const float4*)(W2 + lane16 * 4);
    float part = fmaxf(h[0], 0.f) * w2v.x + fmaxf(h[1], 0.f) * w2v.y +
                 fmaxf(h[2], 0.f) * w2v.z + fmaxf(h[3], 0.f) * w2v.w;
    part += __shfl_xor(part, 8, 16);
    part += __shfl_xor(part, 4, 16);
    part += __shfl_xor(part, 2, 16);
    part += __shfl_xor(part, 1, 16);

    if (lane16 == 0) out[e] = part + b2[0];
}

extern "C" void kernel_launch(void* const* d_in, const int* in_sizes, int n_in,
                              void* d_out, int out_size, void* d_ws, size_t ws_size,
                              hipStream_t stream) {
    const float* Z  = (const float*)d_in[0];
    const int*   EI = (const int*)d_in[1];   // [2, E]: src row then dst row
    const float* W1 = (const float*)d_in[2]; // [256, 64] row-major
    const float* b1 = (const float*)d_in[3]; // [64]
    const float* W2 = (const float*)d_in[4]; // [64]
    const float* b2 = (const float*)d_in[5]; // [1]
    float* out = (float*)d_out;

    const int n_nodes = in_sizes[0] / EMBED;
    const int E       = in_sizes[1] / 2;

    const size_t p_bytes    = (size_t)n_nodes * (2 * HID) * sizeof(ushort); // 25.6 MB
    const size_t frag_bytes = 32 * 64 * 8 * sizeof(ushort);                 // 32 KB each

    if (ws_size >= p_bytes + 2 * frag_bytes) {
        ushort* P     = (ushort*)d_ws;
        ushort* fragH = (ushort*)((char*)d_ws + p_bytes);
        ushort* fragL = (ushort*)((char*)d_ws + p_bytes + frag_bytes);

        frag_prep_kernel<<<8, 256, 0, stream>>>(W1, fragH, fragL);

        const int node_blocks = (n_nodes + 127) / 128;
        node_proj_mfma<<<node_blocks, 256, 0, stream>>>(Z, fragH, fragL, b1, P, n_nodes);

        const int edge_blocks = (E * 8 + 255) / 256;
        edge_mlp_kernel<<<edge_blocks, 256, 0, stream>>>(
            P, EI, EI + E, W2, b2, out, E);
    } else {
        const int edge_blocks = (E * 16 + 255) / 256;
        edge_direct_kernel<<<edge_blocks, 256, 0, stream>>>(
            Z, EI, EI + E, W1, b1, W2, b2, out, E);
    }
}